// Round 11
// baseline (291.987 us; speedup 1.0000x reference)
//
#include <hip/hip_runtime.h>
#include <stdint.h>

#define BN 4096      // N = H*W
#define NCH 256      // C
#define DQ 32        // D = C/8

typedef _Float16 half8  __attribute__((ext_vector_type(8)));
typedef _Float16 half4  __attribute__((ext_vector_type(4)));
typedef _Float16 half2  __attribute__((ext_vector_type(2)));
typedef float   floatx4  __attribute__((ext_vector_type(4)));
typedef float   floatx16 __attribute__((ext_vector_type(16)));

typedef __attribute__((address_space(1))) const void g1_void;
typedef __attribute__((address_space(3))) void l3_void;

#define LOG2E 1.44269504088896f
#define EXP2F(x) __builtin_amdgcn_exp2f(x)
#define LOG2F(x) __builtin_amdgcn_logf(x)

// ---------------------------------------------------------------------------
// convert_w: cast Wq|Wk|Wv (fp32) into one concatenated f16 buffer.
// Wk pre-scaled by log2(e) so scores land in the exp2 domain.
// ---------------------------------------------------------------------------
__global__ __launch_bounds__(256) void convert_w(
    const float* __restrict__ Wq, const float* __restrict__ Wk,
    const float* __restrict__ Wv, _Float16* __restrict__ W16)
{
    int e4 = (blockIdx.x * 256 + threadIdx.x) * 4;
    float4 v;
    if (e4 < 8192)        v = *(const float4*)&Wq[e4];
    else if (e4 < 16384) {
        v = *(const float4*)&Wk[e4 - 8192];
        v.x *= LOG2E; v.y *= LOG2E; v.z *= LOG2E; v.w *= LOG2E;
    }
    else                  v = *(const float4*)&Wv[e4 - 16384];
    half4 h = { (_Float16)v.x, (_Float16)v.y, (_Float16)v.z, (_Float16)v.w };
    *(half4*)&W16[e4] = h;
}

// ---------------------------------------------------------------------------
// MFMA projection (R9 two-block job split).
// ---------------------------------------------------------------------------
__global__ __launch_bounds__(512) void proj_kernel(
    const float* __restrict__ x, const _Float16* __restrict__ W16,
    const float* __restrict__ bq, const float* __restrict__ bk,
    const float* __restrict__ bv,
    _Float16* __restrict__ qT, _Float16* __restrict__ kT,
    _Float16* __restrict__ vb)
{
    const int t  = threadIdx.x;
    const int n0 = blockIdx.x * 128;
    const int b  = blockIdx.z;

    __shared__ __align__(16) _Float16 xTl[128 * 256];  // 64 KB

#pragma unroll
    for (int p = 0; p < 2; ++p) {
        const int kb = p * 128 + (t >> 5) * 8;
        const int n4 = (t & 31) * 4;
        float4 xr[8];
#pragma unroll
        for (int i = 0; i < 8; ++i)
            xr[i] = *(const float4*)&x[((size_t)b * NCH + kb + i) * BN + n0 + n4];
        const float* xf = (const float*)xr;
#pragma unroll
        for (int j = 0; j < 4; ++j) {
            const int n = n4 + j;
            half8 hv;
#pragma unroll
            for (int i = 0; i < 8; ++i) hv[i] = (_Float16)xf[i * 4 + j];
            const int phys = (kb >> 3) ^ ((n >> 2) & 31);
            *(half8*)&xTl[n * 256 + phys * 8] = hv;
        }
    }
    __syncthreads();

    const int lane  = t & 63;
    const int gw    = blockIdx.y * 8 + (t >> 6);   // 0..15
    const int col32 = lane & 31;
    const int h     = lane >> 5;
    const int nc    = gw & 3;
    const int jj    = gw >> 2;                      // 0..3

    const _Float16* Wq16 = W16;
    const _Float16* Wk16 = W16 + 8192;
    const _Float16* Wv16 = W16 + 16384;

#define XFRAG(ks) (*(const half8*)&xTl[(nc * 32 + col32) * 256 + \
        (((ks) * 2 + h) ^ (((nc * 32 + col32) >> 2) & 31)) * 8])

    if (jj == 0) {
        const float bqv = bq[col32];
        const float bkv = bk[col32] * LOG2E;
        floatx16 aq, ak2;
#pragma unroll
        for (int r = 0; r < 16; ++r) { aq[r] = 0.0f; ak2[r] = 0.0f; }
#pragma unroll
        for (int ks = 0; ks < 16; ++ks) {
            half8 xa = XFRAG(ks);
            half8 wqf = *(const half8*)&Wq16[col32 * 256 + ks * 16 + h * 8];
            half8 wkf = *(const half8*)&Wk16[col32 * 256 + ks * 16 + h * 8];
            aq  = __builtin_amdgcn_mfma_f32_32x32x16_f16(xa, wqf, aq, 0, 0, 0);
            ak2 = __builtin_amdgcn_mfma_f32_32x32x16_f16(xa, wkf, ak2, 0, 0, 0);
        }
#pragma unroll
        for (int r = 0; r < 16; ++r) {
            const int n = n0 + nc * 32 + (r & 3) + 8 * (r >> 2) + 4 * h;
            qT[((size_t)b * BN + n) * DQ + col32] = (_Float16)(aq[r] + bqv);
            kT[((size_t)b * BN + n) * DQ + col32] = (_Float16)(ak2[r] + bkv);
        }
    } else {
        const int rg_lo = (jj == 1) ? 0 : (jj == 2) ? 3 : 6;
        const int rg_hi = (jj == 1) ? 3 : (jj == 2) ? 6 : 8;
        for (int rg = rg_lo; rg < rg_hi; ++rg) {
            floatx16 av;
#pragma unroll
            for (int r = 0; r < 16; ++r) av[r] = 0.0f;
#pragma unroll
            for (int ks = 0; ks < 16; ++ks) {
                half8 xb  = XFRAG(ks);
                half8 wvf = *(const half8*)&Wv16[(rg * 32 + col32) * 256 + ks * 16 + h * 8];
                av = __builtin_amdgcn_mfma_f32_32x32x16_f16(wvf, xb, av, 0, 0, 0);
            }
#pragma unroll
            for (int r = 0; r < 16; ++r) {
                const int c = rg * 32 + (r & 3) + 8 * (r >> 2) + 4 * h;
                vb[((size_t)b * NCH + c) * BN + n0 + nc * 32 + col32] =
                    (_Float16)(av[r] + bv[c]);
            }
        }
    }
#undef XFRAG
}

// ---------------------------------------------------------------------------
// MFMA flash attention, key-split. grid (64, nsplit, 8), 256 threads.
// R11: V LDS ROUND-TRIP DELETED. The old global->LDS V DMA used the SAME
// 16B/lane scattered global pattern as a direct per-lane load, so LDS
// staging added no coalescing -- only a round-trip (write 32KB + read
// 32KB per block-iter, ~60% of LDS traffic) and vmcnt choreography.
// av fragments now load straight from global (L2/L3-resident):
//   av[ks][ct] = vp[(w*64+ct*32+col32)*BN + mc + (2ks+h)*8 ..+8]
// issued in two 4-fragment batches (avA after K-prefetch, avB after
// rescale) so L2 latency hides under rescale + Ps reads + first MFMAs.
// LDS = Ps[2] + stats = ~17 KB. Base structure = R9 (proven 116.4 us):
// one lgkm-only barrier/iter, Ps double-buffer, SM(t+1) after PV(t).
// ---------------------------------------------------------------------------
__global__ __launch_bounds__(256, 3) void flash_kernel(
    const _Float16* __restrict__ qT, const _Float16* __restrict__ kT,
    const _Float16* __restrict__ vb,
    _Float16* __restrict__ Op, float* __restrict__ Ml, int KPS)
{
    const int t    = threadIdx.x;
    const int lane = t & 63;
    const int w    = t >> 6;
    const int n0   = blockIdx.x * 64;
    const int kh   = blockIdx.y;
    const int b    = blockIdx.z;
    const int kbase = kh * KPS;
    const int iters = (min(KPS, BN - kbase)) >> 6;

    __shared__ __align__(16) _Float16 Ps[2][64 * 64];  // double-buffered, 2x8 KB
    __shared__ float alph_s[2][64];
    __shared__ float l_s[64];

    const int col   = lane & 15;
    const int q4    = lane >> 4;
    const int col32 = lane & 31;
    const int h     = lane >> 5;

    const _Float16* kp = kT + (size_t)b * BN * DQ;
    const _Float16* vp = vb + (size_t)b * NCH * BN;

    // persistent B_Q frag
    half8 bqf = *(const half8*)&qT[((size_t)b * BN + n0 + w * 16 + col) * DQ + q4 * 8];

    floatx16 acc[2][2];
#pragma unroll
    for (int ct = 0; ct < 2; ++ct)
#pragma unroll
        for (int nt = 0; nt < 2; ++nt)
#pragma unroll
            for (int r = 0; r < 16; ++r) acc[ct][nt][r] = 0.0f;

    float m_i = -1e30f, l_i = 0.0f;

    half8 ak[4];
    half8 avA[2][2], avB[2][2];
    floatx4 sf[4];
    half4 pk[4];
    float al;

#define K_LOAD(MC)                                                          \
    do {                                                                    \
        _Pragma("unroll")                                                   \
        for (int mt = 0; mt < 4; ++mt)                                      \
            ak[mt] = *(const half8*)&kp[(size_t)((MC) + mt * 16 + col) * DQ + q4 * 8]; \
    } while (0)

#define AV_LOAD(DST, MC, KS0)                                               \
    do {                                                                    \
        _Pragma("unroll")                                                   \
        for (int kk = 0; kk < 2; ++kk)                                      \
            _Pragma("unroll")                                               \
            for (int ct = 0; ct < 2; ++ct) {                                \
                const int c = w * 64 + ct * 32 + col32;                     \
                DST[kk][ct] = *(const half8*)&vp[(size_t)c * BN + (MC) + (2 * ((KS0) + kk) + h) * 8]; \
            }                                                               \
    } while (0)

#define QK_STEP()                                                           \
    do {                                                                    \
        __builtin_amdgcn_s_setprio(1);                                      \
        _Pragma("unroll")                                                   \
        for (int mt = 0; mt < 4; ++mt) {                                    \
            floatx4 z = { 0.0f, 0.0f, 0.0f, 0.0f };                         \
            sf[mt] = __builtin_amdgcn_mfma_f32_16x16x32_f16(ak[mt], bqf, z, 0, 0, 0); \
        }                                                                   \
        __builtin_amdgcn_s_setprio(0);                                      \
    } while (0)

#define SM_STEP()                                                           \
    do {                                                                    \
        float cmax = -1e30f;                                                \
        _Pragma("unroll")                                                   \
        for (int mt = 0; mt < 4; ++mt)                                      \
            _Pragma("unroll")                                               \
            for (int r = 0; r < 4; ++r) cmax = fmaxf(cmax, sf[mt][r]);      \
        cmax = fmaxf(cmax, __shfl_xor(cmax, 16));                           \
        cmax = fmaxf(cmax, __shfl_xor(cmax, 32));                           \
        const float mn = (cmax > m_i + 8.0f) ? cmax : m_i;                  \
        al = EXP2F(m_i - mn);                                               \
        float csum = 0.0f;                                                  \
        _Pragma("unroll")                                                   \
        for (int mt = 0; mt < 4; ++mt) {                                    \
            float p0 = EXP2F(sf[mt][0] - mn);                               \
            float p1 = EXP2F(sf[mt][1] - mn);                               \
            float p2 = EXP2F(sf[mt][2] - mn);                               \
            float p3 = EXP2F(sf[mt][3] - mn);                               \
            csum += p0 + p1 + p2 + p3;                                      \
            half2 q01 = __builtin_bit_cast(half2, __builtin_amdgcn_cvt_pkrtz(p0, p1)); \
            half2 q23 = __builtin_bit_cast(half2, __builtin_amdgcn_cvt_pkrtz(p2, p3)); \
            pk[mt][0] = q01[0]; pk[mt][1] = q01[1];                         \
            pk[mt][2] = q23[0]; pk[mt][3] = q23[1];                         \
        }                                                                   \
        csum += __shfl_xor(csum, 16);                                       \
        csum += __shfl_xor(csum, 32);                                       \
        l_i = l_i * al + csum;                                              \
        m_i = mn;                                                           \
    } while (0)

#define PS_WRITE(BUF)                                                       \
    do {                                                                    \
        const int n = w * 16 + col;                                         \
        _Pragma("unroll")                                                   \
        for (int mt = 0; mt < 4; ++mt) {                                    \
            const int p_log = 2 * mt + (q4 >> 1);                           \
            const int p_phys = p_log ^ (n & 7);                             \
            *(half4*)((char*)&Ps[BUF][n * 64] + p_phys * 16 + (q4 & 1) * 8) = pk[mt]; \
        }                                                                   \
        if (q4 == 0) alph_s[BUF][n] = al;                                   \
    } while (0)

#define RESCALE(BUF)                                                        \
    do {                                                                    \
        float a0 = alph_s[BUF][col32];                                      \
        float a1 = alph_s[BUF][32 + col32];                                 \
        if (!__all((a0 == 1.0f) && (a1 == 1.0f))) {                         \
            _Pragma("unroll")                                               \
            for (int ct = 0; ct < 2; ++ct)                                  \
                _Pragma("unroll")                                           \
                for (int r = 0; r < 16; ++r) {                              \
                    acc[ct][0][r] *= a0;                                    \
                    acc[ct][1][r] *= a1;                                    \
                }                                                           \
        }                                                                   \
    } while (0)

// One half of PV: ks = KS0, KS0+1, consuming AV[kk][ct] (direct-loaded V).
#define PV_HALF(AV, BUF, KS0)                                               \
    do {                                                                    \
        _Pragma("unroll")                                                   \
        for (int kk = 0; kk < 2; ++kk) {                                    \
            const int ks = (KS0) + kk;                                      \
            const int p_log = 2 * ks + h;                                   \
            half8 bp0 = *(const half8*)((char*)&Ps[BUF][col32 * 64] + (p_log ^ (col32 & 7)) * 16); \
            half8 bp1 = *(const half8*)((char*)&Ps[BUF][(32 + col32) * 64] + (p_log ^ (col32 & 7)) * 16); \
            acc[0][0] = __builtin_amdgcn_mfma_f32_32x32x16_f16(AV[kk][0], bp0, acc[0][0], 0, 0, 0); \
            acc[0][1] = __builtin_amdgcn_mfma_f32_32x32x16_f16(AV[kk][0], bp1, acc[0][1], 0, 0, 0); \
            acc[1][0] = __builtin_amdgcn_mfma_f32_32x32x16_f16(AV[kk][1], bp0, acc[1][0], 0, 0, 0); \
            acc[1][1] = __builtin_amdgcn_mfma_f32_32x32x16_f16(AV[kk][1], bp1, acc[1][1], 0, 0, 0); \
        }                                                                   \
    } while (0)

    // ---- prologue: tile 0 through softmax ----
    K_LOAD(kbase);
    QK_STEP();
    { const int m1 = (1 < iters) ? kbase + 64 : kbase; K_LOAD(m1); }
    SM_STEP();
    PS_WRITE(0);

    for (int it = 0; it < iters - 1; ++it) {
        const int cur = it & 1, nxt = cur ^ 1;
        const int mc = kbase + it * 64;
        asm volatile("s_waitcnt lgkmcnt(0)" ::: "memory");
        __builtin_amdgcn_s_barrier();           // Ps[cur]/alph[cur] visible
        QK_STEP();                              // consumes ak = K(it+1)
        { const int m2 = (it + 2 < iters) ? kbase + (it + 2) * 64
                                          : kbase + (iters - 1) * 64;
          K_LOAD(m2); }
        AV_LOAD(avA, mc, 0);                    // V(it) first half, in flight
        RESCALE(cur);
        AV_LOAD(avB, mc, 2);                    // V(it) second half
        __builtin_amdgcn_s_setprio(1);
        PV_HALF(avA, cur, 0);                   // compiler waits avA only
        PV_HALF(avB, cur, 2);
        __builtin_amdgcn_s_setprio(0);
        SM_STEP();                              // tile it+1 (VALU, overlaps PV drain)
        PS_WRITE(nxt);
    }

    // ---- final tile ----
    {
        const int cur = (iters - 1) & 1;
        const int mc = kbase + (iters - 1) * 64;
        asm volatile("s_waitcnt lgkmcnt(0)" ::: "memory");
        __builtin_amdgcn_s_barrier();
        AV_LOAD(avA, mc, 0);
        RESCALE(cur);
        AV_LOAD(avB, mc, 2);
        __builtin_amdgcn_s_setprio(1);
        PV_HALF(avA, cur, 0);
        PV_HALF(avB, cur, 2);
        __builtin_amdgcn_s_setprio(0);
    }

    // ---- epilogue: normalized O (f16) + z = m + log2(l) ----
    if (q4 == 0) {
        const int n = w * 16 + col;
        l_s[n] = l_i;
        Ml[(size_t)(kh * 8 + b) * BN + n0 + n] = m_i + LOG2F(l_i);
    }
    __syncthreads();
    const float li0 = 1.0f / l_s[col32];
    const float li1 = 1.0f / l_s[32 + col32];

    _Float16* Opp = Op + (size_t)(kh * 8 + b) * NCH * BN;
#pragma unroll
    for (int ct = 0; ct < 2; ++ct)
#pragma unroll
        for (int nt = 0; nt < 2; ++nt) {
            const float li = nt ? li1 : li0;
#pragma unroll
            for (int r = 0; r < 16; ++r) {
                int row = (r & 3) + 8 * (r >> 2) + 4 * h;
                int c = w * 64 + ct * 32 + row;
                Opp[(size_t)c * BN + n0 + nt * 32 + col32] = (_Float16)(acc[ct][nt][r] * li);
            }
        }
#undef K_LOAD
#undef AV_LOAD
#undef QK_STEP
#undef SM_STEP
#undef PS_WRITE
#undef RESCALE
#undef PV_HALF
}

// ---------------------------------------------------------------------------
// Combine: z-softmax merge of nsplit normalized partials + x residual.
// x8 along n; grid (2, 128, 8) = 2048 blocks, 2 channels/block.
// ---------------------------------------------------------------------------
__global__ __launch_bounds__(256) void combine_kernel(
    const _Float16* __restrict__ Op, const float* __restrict__ Ml,
    const float* __restrict__ x, float* __restrict__ out, int nsplit)
{
    const int n  = (blockIdx.x * 256 + threadIdx.x) * 8;
    const int c0 = blockIdx.y * 2;
    const int b  = blockIdx.z;

    float f[3][8];
    float Z[8];
#pragma unroll
    for (int j = 0; j < 8; ++j) Z[j] = -1e30f;
    for (int s = 0; s < nsplit; ++s) {
        const float* mlp = &Ml[(size_t)(s * 8 + b) * BN + n];
        floatx4 z0 = *(const floatx4*)mlp;
        floatx4 z1 = *(const floatx4*)(mlp + 4);
#pragma unroll
        for (int j = 0; j < 4; ++j) { f[s][j] = z0[j]; f[s][4 + j] = z1[j]; }
#pragma unroll
        for (int j = 0; j < 8; ++j) Z[j] = fmaxf(Z[j], f[s][j]);
    }
    float lsum[8];
#pragma unroll
    for (int j = 0; j < 8; ++j) lsum[j] = 0.0f;
    for (int s = 0; s < nsplit; ++s)
#pragma unroll
        for (int j = 0; j < 8; ++j) { f[s][j] = EXP2F(f[s][j] - Z[j]); lsum[j] += f[s][j]; }
#pragma unroll
    for (int j = 0; j < 8; ++j) lsum[j] = 1.0f / lsum[j];
    for (int s = 0; s < nsplit; ++s)
#pragma unroll
        for (int j = 0; j < 8; ++j) f[s][j] *= lsum[j];

#pragma unroll 2
    for (int ci = 0; ci < 2; ++ci) {
        const int c = c0 + ci;
        const size_t off = ((size_t)b * NCH + c) * BN + n;
        const size_t po = (size_t)c * BN + n;
        float ov[8];
#pragma unroll
        for (int j = 0; j < 8; ++j) ov[j] = 0.0f;
        for (int s = 0; s < nsplit; ++s) {
            half8 hv = *(const half8*)&Op[(size_t)(s * 8 + b) * NCH * BN + po];
#pragma unroll
            for (int j = 0; j < 8; ++j) ov[j] += (float)hv[j] * f[s][j];
        }
        floatx4 x0 = *(const floatx4*)&x[off];
        floatx4 x1 = *(const floatx4*)&x[off + 4];
        floatx4 o0, o1;
#pragma unroll
        for (int j = 0; j < 4; ++j) { o0[j] = ov[j] + x0[j]; o1[j] = ov[4 + j] + x1[j]; }
        *(floatx4*)&out[off] = o0;
        *(floatx4*)&out[off + 4] = o1;
    }
}

extern "C" void kernel_launch(void* const* d_in, const int* in_sizes, int n_in,
                              void* d_out, int out_size, void* d_ws, size_t ws_size,
                              hipStream_t stream)
{
    const float* x  = (const float*)d_in[0];
    const float* Wq = (const float*)d_in[1];
    const float* bq = (const float*)d_in[2];
    const float* Wk = (const float*)d_in[3];
    const float* bk = (const float*)d_in[4];
    const float* Wv = (const float*)d_in[5];
    const float* bv = (const float*)d_in[6];
    float* out = (float*)d_out;

    _Float16* ws = (_Float16*)d_ws;
    _Float16* W16 = ws;                               // 81920 f16
    _Float16* qT  = W16 + 81920;                      // 8*4096*32 f16 (2 MB)
    _Float16* kT  = qT + (size_t)8 * BN * DQ;         // 2 MB
    _Float16* vb  = kT + (size_t)8 * BN * DQ;         // 16 MB
    _Float16* Op  = vb + (size_t)8 * NCH * BN;        // nsplit*16 MB

    // choose split count by available workspace
    const size_t baseElems = 81920 + (size_t)2 * 8 * BN * DQ + (size_t)8 * NCH * BN;
    const size_t opElems3  = (size_t)3 * 8 * NCH * BN;
    const size_t mlBytes   = (size_t)24 * BN * sizeof(float);
    const size_t need3     = (baseElems + opElems3) * 2 + mlBytes + 256;
    const int nsplit = (ws_size >= need3) ? 3 : 2;
    const int KPS    = (nsplit == 3) ? 1408 : 2048;

    float* Ml = (float*)(Op + (size_t)nsplit * 8 * NCH * BN);

    convert_w<<<dim3(80), 256, 0, stream>>>(Wq, Wk, Wv, W16);
    proj_kernel<<<dim3(32, 2, 8), 512, 0, stream>>>(x, W16, bq, bk, bv, qT, kT, vb);
    flash_kernel<<<dim3(64, nsplit, 8), 256, 0, stream>>>(qT, kT, vb, Op, Ml, KPS);
    combine_kernel<<<dim3(2, 128, 8), 256, 0, stream>>>(Op, Ml, x, out, nsplit);
}

// Round 12
// 237.649 us; speedup vs baseline: 1.2286x; 1.2286x over previous
//
#include <hip/hip_runtime.h>
#include <stdint.h>

#define BN 4096      // N = H*W
#define NCH 256      // C
#define DQ 32        // D = C/8

typedef _Float16 half8  __attribute__((ext_vector_type(8)));
typedef _Float16 half4  __attribute__((ext_vector_type(4)));
typedef _Float16 half2  __attribute__((ext_vector_type(2)));
typedef float   floatx4  __attribute__((ext_vector_type(4)));
typedef float   floatx16 __attribute__((ext_vector_type(16)));

typedef __attribute__((address_space(1))) const void g1_void;
typedef __attribute__((address_space(3))) void l3_void;

#define LOG2E 1.44269504088896f
#define EXP2F(x) __builtin_amdgcn_exp2f(x)
#define LOG2F(x) __builtin_amdgcn_logf(x)

// ---------------------------------------------------------------------------
// convert_w: cast Wq|Wk|Wv (fp32) into one concatenated f16 buffer.
// Wk pre-scaled by log2(e) so scores land in the exp2 domain.
// ---------------------------------------------------------------------------
__global__ __launch_bounds__(256) void convert_w(
    const float* __restrict__ Wq, const float* __restrict__ Wk,
    const float* __restrict__ Wv, _Float16* __restrict__ W16)
{
    int e4 = (blockIdx.x * 256 + threadIdx.x) * 4;
    float4 v;
    if (e4 < 8192)        v = *(const float4*)&Wq[e4];
    else if (e4 < 16384) {
        v = *(const float4*)&Wk[e4 - 8192];
        v.x *= LOG2E; v.y *= LOG2E; v.z *= LOG2E; v.w *= LOG2E;
    }
    else                  v = *(const float4*)&Wv[e4 - 16384];
    half4 h = { (_Float16)v.x, (_Float16)v.y, (_Float16)v.z, (_Float16)v.w };
    *(half4*)&W16[e4] = h;
}

// ---------------------------------------------------------------------------
// MFMA projection (proven original: grid (32,8), 512 threads).
// ---------------------------------------------------------------------------
__global__ __launch_bounds__(512) void proj_kernel(
    const float* __restrict__ x, const _Float16* __restrict__ W16,
    const float* __restrict__ bq, const float* __restrict__ bk,
    const float* __restrict__ bv,
    _Float16* __restrict__ qT, _Float16* __restrict__ kT,
    _Float16* __restrict__ vb)
{
    const int t  = threadIdx.x;
    const int n0 = blockIdx.x * 128;
    const int b  = blockIdx.y;

    __shared__ __align__(16) _Float16 xTl[128 * 256];  // 64 KB

#pragma unroll
    for (int p = 0; p < 2; ++p) {
        const int kb = p * 128 + (t >> 5) * 8;
        const int n4 = (t & 31) * 4;
        float4 xr[8];
#pragma unroll
        for (int i = 0; i < 8; ++i)
            xr[i] = *(const float4*)&x[((size_t)b * NCH + kb + i) * BN + n0 + n4];
        const float* xf = (const float*)xr;
#pragma unroll
        for (int j = 0; j < 4; ++j) {
            const int n = n4 + j;
            half8 hv;
#pragma unroll
            for (int i = 0; i < 8; ++i) hv[i] = (_Float16)xf[i * 4 + j];
            const int phys = (kb >> 3) ^ ((n >> 2) & 31);
            *(half8*)&xTl[n * 256 + phys * 8] = hv;
        }
    }
    __syncthreads();

    const int lane  = t & 63;
    const int w     = t >> 6;
    const int col32 = lane & 31;
    const int h     = lane >> 5;
    const int nc    = w & 3;
    const int job   = w >> 2;

    const _Float16* Wq16 = W16;
    const _Float16* Wk16 = W16 + 8192;
    const _Float16* Wv16 = W16 + 16384;

#define XFRAG(ks) (*(const half8*)&xTl[(nc * 32 + col32) * 256 + \
        (((ks) * 2 + h) ^ (((nc * 32 + col32) >> 2) & 31)) * 8])

    if (job == 0) {
        const float bqv = bq[col32];
        const float bkv = bk[col32] * LOG2E;
        floatx16 aq, ak2;
#pragma unroll
        for (int r = 0; r < 16; ++r) { aq[r] = 0.0f; ak2[r] = 0.0f; }
#pragma unroll
        for (int ks = 0; ks < 16; ++ks) {
            half8 xa = XFRAG(ks);
            half8 wqf = *(const half8*)&Wq16[col32 * 256 + ks * 16 + h * 8];
            half8 wkf = *(const half8*)&Wk16[col32 * 256 + ks * 16 + h * 8];
            aq  = __builtin_amdgcn_mfma_f32_32x32x16_f16(xa, wqf, aq, 0, 0, 0);
            ak2 = __builtin_amdgcn_mfma_f32_32x32x16_f16(xa, wkf, ak2, 0, 0, 0);
        }
#pragma unroll
        for (int r = 0; r < 16; ++r) {
            const int n = n0 + nc * 32 + (r & 3) + 8 * (r >> 2) + 4 * h;
            qT[((size_t)b * BN + n) * DQ + col32] = (_Float16)(aq[r] + bqv);
            kT[((size_t)b * BN + n) * DQ + col32] = (_Float16)(ak2[r] + bkv);
        }
    }

    const int rg_lo = (job == 0) ? 0 : 3;
    const int rg_hi = (job == 0) ? 3 : 8;
    for (int rg = rg_lo; rg < rg_hi; ++rg) {
        floatx16 av;
#pragma unroll
        for (int r = 0; r < 16; ++r) av[r] = 0.0f;
#pragma unroll
        for (int ks = 0; ks < 16; ++ks) {
            half8 xb  = XFRAG(ks);
            half8 wvf = *(const half8*)&Wv16[(rg * 32 + col32) * 256 + ks * 16 + h * 8];
            av = __builtin_amdgcn_mfma_f32_32x32x16_f16(wvf, xb, av, 0, 0, 0);
        }
#pragma unroll
        for (int r = 0; r < 16; ++r) {
            const int c = rg * 32 + (r & 3) + 8 * (r >> 2) + 4 * h;
            vb[((size_t)b * NCH + c) * BN + n0 + nc * 32 + col32] =
                (_Float16)(av[r] + bv[c]);
        }
    }
#undef XFRAG
}

// ---------------------------------------------------------------------------
// MFMA flash attention, key-split. grid (64, nsplit, 8).
// PROVEN BEST (R7, 116.4 us): software-pipelined loop -- SM(t+1) overlaps
// PV(t) drain; one lgkm-only barrier/iter; Ps double-buffer; counted
// vmcnt(4) before PV; V staged via global_load_lds (the DMA is the
// coalescer: 8 rows x 128B segments/wave vs 32 rows x 32B direct — R11
// proved direct-load de-coalesces, 186 us). Wave-fusion (R1/R2),
// producer/consumer (R8/R10) both register-blocked: acc 64 f32 + operands
// ~148 regs caps 3 waves/SIMD regardless of structure.
// ---------------------------------------------------------------------------
__global__ __launch_bounds__(256, 3) void flash_kernel(
    const _Float16* __restrict__ qT, const _Float16* __restrict__ kT,
    const _Float16* __restrict__ vb,
    _Float16* __restrict__ Op, float* __restrict__ Ml, int KPS)
{
    const int t    = threadIdx.x;
    const int lane = t & 63;
    const int w    = t >> 6;
    const int n0   = blockIdx.x * 64;
    const int kh   = blockIdx.y;
    const int b    = blockIdx.z;
    const int kbase = kh * KPS;
    const int iters = (min(KPS, BN - kbase)) >> 6;

    __shared__ __align__(16) _Float16 vs[NCH * 64];    // [c][seg^], 32 KB, wave-private rows
    __shared__ __align__(16) _Float16 Ps[2][64 * 64];  // double-buffered, 2x8 KB
    __shared__ float alph_s[2][64];
    __shared__ float l_s[64];

    const int col   = lane & 15;
    const int q4    = lane >> 4;
    const int col32 = lane & 31;
    const int h     = lane >> 5;

    const _Float16* kp = kT + (size_t)b * BN * DQ;
    const _Float16* vp = vb + (size_t)b * NCH * BN;

    // persistent B_Q frag
    half8 bqf = *(const half8*)&qT[((size_t)b * BN + n0 + w * 16 + col) * DQ + q4 * 8];

    floatx16 acc[2][2];
#pragma unroll
    for (int ct = 0; ct < 2; ++ct)
#pragma unroll
        for (int nt = 0; nt < 2; ++nt)
#pragma unroll
            for (int r = 0; r < 16; ++r) acc[ct][nt][r] = 0.0f;

    float m_i = -1e30f, l_i = 0.0f;

    const int sc_loc = lane >> 3;
    const int s_log  = (lane & 7) ^ (sc_loc & 7);

    half8 ak[4];
    floatx4 sf[4];
    half4 pk[4];
    float al;

#define K_LOAD(MC)                                                          \
    do {                                                                    \
        _Pragma("unroll")                                                   \
        for (int mt = 0; mt < 4; ++mt)                                      \
            ak[mt] = *(const half8*)&kp[(size_t)((MC) + mt * 16 + col) * DQ + q4 * 8]; \
    } while (0)

#define V_DMA(MC)                                                           \
    do {                                                                    \
        _Pragma("unroll")                                                   \
        for (int j = 0; j < 8; ++j) {                                       \
            const int c = w * 64 + j * 8 + sc_loc;                          \
            __builtin_amdgcn_global_load_lds(                               \
                (g1_void*)&vp[(size_t)c * BN + (MC) + s_log * 8],           \
                (l3_void*)&vs[(w * 64 + j * 8) * 64], 16, 0, 0);            \
        }                                                                   \
    } while (0)

#define QK_STEP()                                                           \
    do {                                                                    \
        __builtin_amdgcn_s_setprio(1);                                      \
        _Pragma("unroll")                                                   \
        for (int mt = 0; mt < 4; ++mt) {                                    \
            floatx4 z = { 0.0f, 0.0f, 0.0f, 0.0f };                         \
            sf[mt] = __builtin_amdgcn_mfma_f32_16x16x32_f16(ak[mt], bqf, z, 0, 0, 0); \
        }                                                                   \
        __builtin_amdgcn_s_setprio(0);                                      \
    } while (0)

#define SM_STEP()                                                           \
    do {                                                                    \
        float cmax = -1e30f;                                                \
        _Pragma("unroll")                                                   \
        for (int mt = 0; mt < 4; ++mt)                                      \
            _Pragma("unroll")                                               \
            for (int r = 0; r < 4; ++r) cmax = fmaxf(cmax, sf[mt][r]);      \
        cmax = fmaxf(cmax, __shfl_xor(cmax, 16));                           \
        cmax = fmaxf(cmax, __shfl_xor(cmax, 32));                           \
        const float mn = (cmax > m_i + 8.0f) ? cmax : m_i;                  \
        al = EXP2F(m_i - mn);                                               \
        float csum = 0.0f;                                                  \
        _Pragma("unroll")                                                   \
        for (int mt = 0; mt < 4; ++mt) {                                    \
            float p0 = EXP2F(sf[mt][0] - mn);                               \
            float p1 = EXP2F(sf[mt][1] - mn);                               \
            float p2 = EXP2F(sf[mt][2] - mn);                               \
            float p3 = EXP2F(sf[mt][3] - mn);                               \
            csum += p0 + p1 + p2 + p3;                                      \
            half2 q01 = __builtin_bit_cast(half2, __builtin_amdgcn_cvt_pkrtz(p0, p1)); \
            half2 q23 = __builtin_bit_cast(half2, __builtin_amdgcn_cvt_pkrtz(p2, p3)); \
            pk[mt][0] = q01[0]; pk[mt][1] = q01[1];                         \
            pk[mt][2] = q23[0]; pk[mt][3] = q23[1];                         \
        }                                                                   \
        csum += __shfl_xor(csum, 16);                                       \
        csum += __shfl_xor(csum, 32);                                       \
        l_i = l_i * al + csum;                                              \
        m_i = mn;                                                           \
    } while (0)

#define PS_WRITE(BUF)                                                       \
    do {                                                                    \
        const int n = w * 16 + col;                                         \
        _Pragma("unroll")                                                   \
        for (int mt = 0; mt < 4; ++mt) {                                    \
            const int p_log = 2 * mt + (q4 >> 1);                           \
            const int p_phys = p_log ^ (n & 7);                             \
            *(half4*)((char*)&Ps[BUF][n * 64] + p_phys * 16 + (q4 & 1) * 8) = pk[mt]; \
        }                                                                   \
        if (q4 == 0) alph_s[BUF][n] = al;                                   \
    } while (0)

#define RESCALE(BUF)                                                        \
    do {                                                                    \
        float a0 = alph_s[BUF][col32];                                      \
        float a1 = alph_s[BUF][32 + col32];                                 \
        if (!__all((a0 == 1.0f) && (a1 == 1.0f))) {                         \
            _Pragma("unroll")                                               \
            for (int ct = 0; ct < 2; ++ct)                                  \
                _Pragma("unroll")                                           \
                for (int r = 0; r < 16; ++r) {                              \
                    acc[ct][0][r] *= a0;                                    \
                    acc[ct][1][r] *= a1;                                    \
                }                                                           \
        }                                                                   \
    } while (0)

#define PV_STEP(BUF)                                                        \
    do {                                                                    \
        __builtin_amdgcn_s_setprio(1);                                      \
        _Pragma("unroll")                                                   \
        for (int ks = 0; ks < 4; ++ks) {                                    \
            const int p_log = 2 * ks + h;                                   \
            half8 bp0 = *(const half8*)((char*)&Ps[BUF][col32 * 64] + (p_log ^ (col32 & 7)) * 16); \
            half8 bp1 = *(const half8*)((char*)&Ps[BUF][(32 + col32) * 64] + (p_log ^ (col32 & 7)) * 16); \
            _Pragma("unroll")                                               \
            for (int ct = 0; ct < 2; ++ct) {                                \
                const int c = w * 64 + ct * 32 + col32;                     \
                half8 av = *(const half8*)((char*)&vs[c * 64] + ((p_log ^ (c & 7)) * 16)); \
                acc[ct][0] = __builtin_amdgcn_mfma_f32_32x32x16_f16(av, bp0, acc[ct][0], 0, 0, 0); \
                acc[ct][1] = __builtin_amdgcn_mfma_f32_32x32x16_f16(av, bp1, acc[ct][1], 0, 0, 0); \
            }                                                               \
        }                                                                   \
        __builtin_amdgcn_s_setprio(0);                                      \
    } while (0)

    // ---- prologue: tile 0 through softmax ----
    K_LOAD(kbase);          // 4 VMEM (oldest)
    V_DMA(kbase);           // 8 VMEM
    QK_STEP();              // auto-wait on ak leaves V0 in flight
    { const int m1 = (1 < iters) ? kbase + 64 : kbase; K_LOAD(m1); }
    SM_STEP();
    PS_WRITE(0);

    for (int it = 0; it < iters - 1; ++it) {
        const int cur = it & 1, nxt = cur ^ 1;
        asm volatile("s_waitcnt lgkmcnt(0)" ::: "memory");
        __builtin_amdgcn_s_barrier();           // Ps[cur]/alph[cur] visible
        QK_STEP();                              // consumes ak = K(it+1)
        { const int m2 = (it + 2 < iters) ? kbase + (it + 2) * 64
                                          : kbase + (iters - 1) * 64;
          K_LOAD(m2); }
        RESCALE(cur);
        asm volatile("s_waitcnt vmcnt(4)" ::: "memory");  // V(it) landed
        PV_STEP(cur);
        SM_STEP();                              // overlaps PV drain (VALU pipe)
        PS_WRITE(nxt);
        asm volatile("s_waitcnt lgkmcnt(0)" ::: "memory"); // my PV reads retired
        V_DMA(kbase + (it + 1) * 64);
    }

    // ---- final tile ----
    {
        const int cur = (iters - 1) & 1;
        asm volatile("s_waitcnt lgkmcnt(0)" ::: "memory");
        __builtin_amdgcn_s_barrier();
        RESCALE(cur);
        asm volatile("s_waitcnt vmcnt(0)" ::: "memory");  // age order inverted: full drain
        PV_STEP(cur);
    }

    // ---- epilogue: normalized O (f16) + z = m + log2(l) ----
    if (q4 == 0) {
        const int n = w * 16 + col;
        l_s[n] = l_i;
        Ml[(size_t)(kh * 8 + b) * BN + n0 + n] = m_i + LOG2F(l_i);
    }
    __syncthreads();
    const float li0 = 1.0f / l_s[col32];
    const float li1 = 1.0f / l_s[32 + col32];

    _Float16* Opp = Op + (size_t)(kh * 8 + b) * NCH * BN;
#pragma unroll
    for (int ct = 0; ct < 2; ++ct)
#pragma unroll
        for (int nt = 0; nt < 2; ++nt) {
            const float li = nt ? li1 : li0;
#pragma unroll
            for (int r = 0; r < 16; ++r) {
                int row = (r & 3) + 8 * (r >> 2) + 4 * h;
                int c = w * 64 + ct * 32 + row;
                Opp[(size_t)c * BN + n0 + nt * 32 + col32] = (_Float16)(acc[ct][nt][r] * li);
            }
        }
#undef K_LOAD
#undef V_DMA
#undef QK_STEP
#undef SM_STEP
#undef PS_WRITE
#undef RESCALE
#undef PV_STEP
}

// ---------------------------------------------------------------------------
// Combine: z-softmax merge of nsplit normalized partials + x residual.
// x8 along n; grid (2, 128, 8) = 2048 blocks, 2 channels/block.
// ---------------------------------------------------------------------------
__global__ __launch_bounds__(256) void combine_kernel(
    const _Float16* __restrict__ Op, const float* __restrict__ Ml,
    const float* __restrict__ x, float* __restrict__ out, int nsplit)
{
    const int n  = (blockIdx.x * 256 + threadIdx.x) * 8;
    const int c0 = blockIdx.y * 2;
    const int b  = blockIdx.z;

    float f[3][8];
    float Z[8];
#pragma unroll
    for (int j = 0; j < 8; ++j) Z[j] = -1e30f;
    for (int s = 0; s < nsplit; ++s) {
        const float* mlp = &Ml[(size_t)(s * 8 + b) * BN + n];
        floatx4 z0 = *(const floatx4*)mlp;
        floatx4 z1 = *(const floatx4*)(mlp + 4);
#pragma unroll
        for (int j = 0; j < 4; ++j) { f[s][j] = z0[j]; f[s][4 + j] = z1[j]; }
#pragma unroll
        for (int j = 0; j < 8; ++j) Z[j] = fmaxf(Z[j], f[s][j]);
    }
    float lsum[8];
#pragma unroll
    for (int j = 0; j < 8; ++j) lsum[j] = 0.0f;
    for (int s = 0; s < nsplit; ++s)
#pragma unroll
        for (int j = 0; j < 8; ++j) { f[s][j] = EXP2F(f[s][j] - Z[j]); lsum[j] += f[s][j]; }
#pragma unroll
    for (int j = 0; j < 8; ++j) lsum[j] = 1.0f / lsum[j];
    for (int s = 0; s < nsplit; ++s)
#pragma unroll
        for (int j = 0; j < 8; ++j) f[s][j] *= lsum[j];

#pragma unroll 2
    for (int ci = 0; ci < 2; ++ci) {
        const int c = c0 + ci;
        const size_t off = ((size_t)b * NCH + c) * BN + n;
        const size_t po = (size_t)c * BN + n;
        float ov[8];
#pragma unroll
        for (int j = 0; j < 8; ++j) ov[j] = 0.0f;
        for (int s = 0; s < nsplit; ++s) {
            half8 hv = *(const half8*)&Op[(size_t)(s * 8 + b) * NCH * BN + po];
#pragma unroll
            for (int j = 0; j < 8; ++j) ov[j] += (float)hv[j] * f[s][j];
        }
        floatx4 x0 = *(const floatx4*)&x[off];
        floatx4 x1 = *(const floatx4*)&x[off + 4];
        floatx4 o0, o1;
#pragma unroll
        for (int j = 0; j < 4; ++j) { o0[j] = ov[j] + x0[j]; o1[j] = ov[4 + j] + x1[j]; }
        *(floatx4*)&out[off] = o0;
        *(floatx4*)&out[off + 4] = o1;
    }
}

extern "C" void kernel_launch(void* const* d_in, const int* in_sizes, int n_in,
                              void* d_out, int out_size, void* d_ws, size_t ws_size,
                              hipStream_t stream)
{
    const float* x  = (const float*)d_in[0];
    const float* Wq = (const float*)d_in[1];
    const float* bq = (const float*)d_in[2];
    const float* Wk = (const float*)d_in[3];
    const float* bk = (const float*)d_in[4];
    const float* Wv = (const float*)d_in[5];
    const float* bv = (const float*)d_in[6];
    float* out = (float*)d_out;

    _Float16* ws = (_Float16*)d_ws;
    _Float16* W16 = ws;                               // 81920 f16
    _Float16* qT  = W16 + 81920;                      // 8*4096*32 f16 (2 MB)
    _Float16* kT  = qT + (size_t)8 * BN * DQ;         // 2 MB
    _Float16* vb  = kT + (size_t)8 * BN * DQ;         // 16 MB
    _Float16* Op  = vb + (size_t)8 * NCH * BN;        // nsplit*16 MB

    // choose split count by available workspace
    const size_t baseElems = 81920 + (size_t)2 * 8 * BN * DQ + (size_t)8 * NCH * BN;
    const size_t opElems3  = (size_t)3 * 8 * NCH * BN;
    const size_t mlBytes   = (size_t)24 * BN * sizeof(float);
    const size_t need3     = (baseElems + opElems3) * 2 + mlBytes + 256;
    const int nsplit = (ws_size >= need3) ? 3 : 2;
    const int KPS    = (nsplit == 3) ? 1408 : 2048;

    float* Ml = (float*)(Op + (size_t)nsplit * 8 * NCH * BN);

    convert_w<<<dim3(80), 256, 0, stream>>>(Wq, Wk, Wv, W16);
    proj_kernel<<<dim3(32, 8), 512, 0, stream>>>(x, W16, bq, bk, bv, qT, kT, vb);
    flash_kernel<<<dim3(64, nsplit, 8), 256, 0, stream>>>(qT, kT, vb, Op, Ml, KPS);
    combine_kernel<<<dim3(2, 128, 8), 256, 0, stream>>>(Op, Ml, x, out, nsplit);
}

// Round 14
// 235.647 us; speedup vs baseline: 1.2391x; 1.0085x over previous
//
#include <hip/hip_runtime.h>
#include <stdint.h>

#define BN 4096      // N = H*W
#define NCH 256      // C
#define DQ 32        // D = C/8

typedef _Float16 half8  __attribute__((ext_vector_type(8)));
typedef _Float16 half4  __attribute__((ext_vector_type(4)));
typedef _Float16 half2  __attribute__((ext_vector_type(2)));
typedef float   floatx4  __attribute__((ext_vector_type(4)));
typedef float   floatx16 __attribute__((ext_vector_type(16)));

typedef __attribute__((address_space(1))) const void g1_void;
typedef __attribute__((address_space(3))) void l3_void;

#define LOG2E 1.44269504088896f
#define EXP2F(x) __builtin_amdgcn_exp2f(x)
#define LOG2F(x) __builtin_amdgcn_logf(x)

// ---------------------------------------------------------------------------
// convert_w: cast Wq|Wk|Wv (fp32) into one concatenated f16 buffer.
// Wk pre-scaled by log2(e) so scores land in the exp2 domain.
// ---------------------------------------------------------------------------
__global__ __launch_bounds__(256) void convert_w(
    const float* __restrict__ Wq, const float* __restrict__ Wk,
    const float* __restrict__ Wv, _Float16* __restrict__ W16)
{
    int e4 = (blockIdx.x * 256 + threadIdx.x) * 4;
    float4 v;
    if (e4 < 8192)        v = *(const float4*)&Wq[e4];
    else if (e4 < 16384) {
        v = *(const float4*)&Wk[e4 - 8192];
        v.x *= LOG2E; v.y *= LOG2E; v.z *= LOG2E; v.w *= LOG2E;
    }
    else                  v = *(const float4*)&Wv[e4 - 16384];
    half4 h = { (_Float16)v.x, (_Float16)v.y, (_Float16)v.z, (_Float16)v.w };
    *(half4*)&W16[e4] = h;
}

// ---------------------------------------------------------------------------
// MFMA projection. R13: interleaved accumulator chains.
// Old: each wave ran 5 SERIAL 16-MFMA accumulation chains (each MFMA
// dependent on the previous, ~16-32cyc, only 2 waves/SIMD of cover ->
// latency-bound). New: 2 phases/wave of 2-3 INTERLEAVED chains sharing
// one XFRAG read:  job0: (Q,K) pair + (rg0,rg1,rg2) triple;
//                  job1: (rg3,rg4,rg5) triple + (rg6,rg7) pair.
// 3x MFMA ILP in triple phases + XFRAG LDS reads cut ~2.5x. Staging,
// swizzle, and store index math byte-identical to the proven version.
// (R9's block-split failed because it DUPLICATED the 64KB staging; this
// keeps staging single and fixes the chain structure instead.)
// ---------------------------------------------------------------------------
__global__ __launch_bounds__(512) void proj_kernel(
    const float* __restrict__ x, const _Float16* __restrict__ W16,
    const float* __restrict__ bq, const float* __restrict__ bk,
    const float* __restrict__ bv,
    _Float16* __restrict__ qT, _Float16* __restrict__ kT,
    _Float16* __restrict__ vb)
{
    const int t  = threadIdx.x;
    const int n0 = blockIdx.x * 128;
    const int b  = blockIdx.y;

    __shared__ __align__(16) _Float16 xTl[128 * 256];  // 64 KB

#pragma unroll
    for (int p = 0; p < 2; ++p) {
        const int kb = p * 128 + (t >> 5) * 8;
        const int n4 = (t & 31) * 4;
        float4 xr[8];
#pragma unroll
        for (int i = 0; i < 8; ++i)
            xr[i] = *(const float4*)&x[((size_t)b * NCH + kb + i) * BN + n0 + n4];
        const float* xf = (const float*)xr;
#pragma unroll
        for (int j = 0; j < 4; ++j) {
            const int n = n4 + j;
            half8 hv;
#pragma unroll
            for (int i = 0; i < 8; ++i) hv[i] = (_Float16)xf[i * 4 + j];
            const int phys = (kb >> 3) ^ ((n >> 2) & 31);
            *(half8*)&xTl[n * 256 + phys * 8] = hv;
        }
    }
    __syncthreads();

    const int lane  = t & 63;
    const int w     = t >> 6;
    const int col32 = lane & 31;
    const int h     = lane >> 5;
    const int nc    = w & 3;
    const int job   = w >> 2;

    const _Float16* Wq16 = W16;
    const _Float16* Wk16 = W16 + 8192;
    const _Float16* Wv16 = W16 + 16384;

#define XFRAG(ks) (*(const half8*)&xTl[(nc * 32 + col32) * 256 + \
        (((ks) * 2 + h) ^ (((nc * 32 + col32) >> 2) & 31)) * 8])

#define VSTORE(RG, AV)                                                      \
    do {                                                                    \
        _Pragma("unroll")                                                   \
        for (int r = 0; r < 16; ++r) {                                      \
            const int c = (RG) * 32 + (r & 3) + 8 * (r >> 2) + 4 * h;       \
            vb[((size_t)b * NCH + c) * BN + n0 + nc * 32 + col32] =         \
                (_Float16)(AV[r] + bv[c]);                                  \
        }                                                                   \
    } while (0)

#define RG_TRIPLE(R0)                                                       \
    do {                                                                    \
        floatx16 a0, a1, a2;                                                \
        _Pragma("unroll")                                                   \
        for (int r = 0; r < 16; ++r) { a0[r] = 0.0f; a1[r] = 0.0f; a2[r] = 0.0f; } \
        _Pragma("unroll")                                                   \
        for (int ks = 0; ks < 16; ++ks) {                                   \
            half8 xb = XFRAG(ks);                                           \
            half8 w0 = *(const half8*)&Wv16[(((R0) + 0) * 32 + col32) * 256 + ks * 16 + h * 8]; \
            half8 w1 = *(const half8*)&Wv16[(((R0) + 1) * 32 + col32) * 256 + ks * 16 + h * 8]; \
            half8 w2 = *(const half8*)&Wv16[(((R0) + 2) * 32 + col32) * 256 + ks * 16 + h * 8]; \
            a0 = __builtin_amdgcn_mfma_f32_32x32x16_f16(w0, xb, a0, 0, 0, 0); \
            a1 = __builtin_amdgcn_mfma_f32_32x32x16_f16(w1, xb, a1, 0, 0, 0); \
            a2 = __builtin_amdgcn_mfma_f32_32x32x16_f16(w2, xb, a2, 0, 0, 0); \
        }                                                                   \
        VSTORE((R0) + 0, a0);                                               \
        VSTORE((R0) + 1, a1);                                               \
        VSTORE((R0) + 2, a2);                                               \
    } while (0)

#define RG_PAIR(R0)                                                         \
    do {                                                                    \
        floatx16 a0, a1;                                                    \
        _Pragma("unroll")                                                   \
        for (int r = 0; r < 16; ++r) { a0[r] = 0.0f; a1[r] = 0.0f; }        \
        _Pragma("unroll")                                                   \
        for (int ks = 0; ks < 16; ++ks) {                                   \
            half8 xb = XFRAG(ks);                                           \
            half8 w0 = *(const half8*)&Wv16[(((R0) + 0) * 32 + col32) * 256 + ks * 16 + h * 8]; \
            half8 w1 = *(const half8*)&Wv16[(((R0) + 1) * 32 + col32) * 256 + ks * 16 + h * 8]; \
            a0 = __builtin_amdgcn_mfma_f32_32x32x16_f16(w0, xb, a0, 0, 0, 0); \
            a1 = __builtin_amdgcn_mfma_f32_32x32x16_f16(w1, xb, a1, 0, 0, 0); \
        }                                                                   \
        VSTORE((R0) + 0, a0);                                               \
        VSTORE((R0) + 1, a1);                                               \
    } while (0)

    if (job == 0) {
        // phase 1: Q + K (2 interleaved chains, shared xa)
        const float bqv = bq[col32];
        const float bkv = bk[col32] * LOG2E;
        floatx16 aq, ak2;
#pragma unroll
        for (int r = 0; r < 16; ++r) { aq[r] = 0.0f; ak2[r] = 0.0f; }
#pragma unroll
        for (int ks = 0; ks < 16; ++ks) {
            half8 xa = XFRAG(ks);
            half8 wqf = *(const half8*)&Wq16[col32 * 256 + ks * 16 + h * 8];
            half8 wkf = *(const half8*)&Wk16[col32 * 256 + ks * 16 + h * 8];
            aq  = __builtin_amdgcn_mfma_f32_32x32x16_f16(xa, wqf, aq, 0, 0, 0);
            ak2 = __builtin_amdgcn_mfma_f32_32x32x16_f16(xa, wkf, ak2, 0, 0, 0);
        }
#pragma unroll
        for (int r = 0; r < 16; ++r) {
            const int n = n0 + nc * 32 + (r & 3) + 8 * (r >> 2) + 4 * h;
            qT[((size_t)b * BN + n) * DQ + col32] = (_Float16)(aq[r] + bqv);
            kT[((size_t)b * BN + n) * DQ + col32] = (_Float16)(ak2[r] + bkv);
        }
        // phase 2: rg0..2 (3 interleaved chains)
        RG_TRIPLE(0);
    } else {
        // phase 1: rg3..5 (3 interleaved chains); phase 2: rg6..7 (pair)
        RG_TRIPLE(3);
        RG_PAIR(6);
    }
#undef XFRAG
#undef VSTORE
#undef RG_TRIPLE
#undef RG_PAIR
}

// ---------------------------------------------------------------------------
// MFMA flash attention, key-split. grid (64, nsplit, 8).
// PROVEN BEST structure (R7/R12, 116.9 us) + R13 micro: ballot-gated cmax
// shuffles -- when __all(lane_cmax <= m_i+8) (defer-max common case) the
// two ds_permute row-max shuffles are skipped; mn = m_i stays row-uniform
// by induction. V stays LDS-staged (R11 proved direct V load de-coalesces:
// DMA = 8 rows x 128B segments/wave vs 32 rows x 32B direct).
// ---------------------------------------------------------------------------
__global__ __launch_bounds__(256, 3) void flash_kernel(
    const _Float16* __restrict__ qT, const _Float16* __restrict__ kT,
    const _Float16* __restrict__ vb,
    _Float16* __restrict__ Op, float* __restrict__ Ml, int KPS)
{
    const int t    = threadIdx.x;
    const int lane = t & 63;
    const int w    = t >> 6;
    const int n0   = blockIdx.x * 64;
    const int kh   = blockIdx.y;
    const int b    = blockIdx.z;
    const int kbase = kh * KPS;
    const int iters = (min(KPS, BN - kbase)) >> 6;

    __shared__ __align__(16) _Float16 vs[NCH * 64];    // [c][seg^], 32 KB, wave-private rows
    __shared__ __align__(16) _Float16 Ps[2][64 * 64];  // double-buffered, 2x8 KB
    __shared__ float alph_s[2][64];
    __shared__ float l_s[64];

    const int col   = lane & 15;
    const int q4    = lane >> 4;
    const int col32 = lane & 31;
    const int h     = lane >> 5;

    const _Float16* kp = kT + (size_t)b * BN * DQ;
    const _Float16* vp = vb + (size_t)b * NCH * BN;

    // persistent B_Q frag
    half8 bqf = *(const half8*)&qT[((size_t)b * BN + n0 + w * 16 + col) * DQ + q4 * 8];

    floatx16 acc[2][2];
#pragma unroll
    for (int ct = 0; ct < 2; ++ct)
#pragma unroll
        for (int nt = 0; nt < 2; ++nt)
#pragma unroll
            for (int r = 0; r < 16; ++r) acc[ct][nt][r] = 0.0f;

    float m_i = -1e30f, l_i = 0.0f;

    const int sc_loc = lane >> 3;
    const int s_log  = (lane & 7) ^ (sc_loc & 7);

    half8 ak[4];
    floatx4 sf[4];
    half4 pk[4];
    float al;

#define K_LOAD(MC)                                                          \
    do {                                                                    \
        _Pragma("unroll")                                                   \
        for (int mt = 0; mt < 4; ++mt)                                      \
            ak[mt] = *(const half8*)&kp[(size_t)((MC) + mt * 16 + col) * DQ + q4 * 8]; \
    } while (0)

#define V_DMA(MC)                                                           \
    do {                                                                    \
        _Pragma("unroll")                                                   \
        for (int j = 0; j < 8; ++j) {                                       \
            const int c = w * 64 + j * 8 + sc_loc;                          \
            __builtin_amdgcn_global_load_lds(                               \
                (g1_void*)&vp[(size_t)c * BN + (MC) + s_log * 8],           \
                (l3_void*)&vs[(w * 64 + j * 8) * 64], 16, 0, 0);            \
        }                                                                   \
    } while (0)

#define QK_STEP()                                                           \
    do {                                                                    \
        __builtin_amdgcn_s_setprio(1);                                      \
        _Pragma("unroll")                                                   \
        for (int mt = 0; mt < 4; ++mt) {                                    \
            floatx4 z = { 0.0f, 0.0f, 0.0f, 0.0f };                         \
            sf[mt] = __builtin_amdgcn_mfma_f32_16x16x32_f16(ak[mt], bqf, z, 0, 0, 0); \
        }                                                                   \
        __builtin_amdgcn_s_setprio(0);                                      \
    } while (0)

#define SM_STEP()                                                           \
    do {                                                                    \
        float cmax = -1e30f;                                                \
        _Pragma("unroll")                                                   \
        for (int mt = 0; mt < 4; ++mt)                                      \
            _Pragma("unroll")                                               \
            for (int r = 0; r < 4; ++r) cmax = fmaxf(cmax, sf[mt][r]);      \
        if (!__all(cmax <= m_i + 8.0f)) {                                   \
            cmax = fmaxf(cmax, __shfl_xor(cmax, 16));                       \
            cmax = fmaxf(cmax, __shfl_xor(cmax, 32));                       \
        }                                                                   \
        const float mn = (cmax > m_i + 8.0f) ? cmax : m_i;                  \
        al = EXP2F(m_i - mn);                                               \
        float csum = 0.0f;                                                  \
        _Pragma("unroll")                                                   \
        for (int mt = 0; mt < 4; ++mt) {                                    \
            float p0 = EXP2F(sf[mt][0] - mn);                               \
            float p1 = EXP2F(sf[mt][1] - mn);                               \
            float p2 = EXP2F(sf[mt][2] - mn);                               \
            float p3 = EXP2F(sf[mt][3] - mn);                               \
            csum += p0 + p1 + p2 + p3;                                      \
            half2 q01 = __builtin_bit_cast(half2, __builtin_amdgcn_cvt_pkrtz(p0, p1)); \
            half2 q23 = __builtin_bit_cast(half2, __builtin_amdgcn_cvt_pkrtz(p2, p3)); \
            pk[mt][0] = q01[0]; pk[mt][1] = q01[1];                         \
            pk[mt][2] = q23[0]; pk[mt][3] = q23[1];                         \
        }                                                                   \
        csum += __shfl_xor(csum, 16);                                       \
        csum += __shfl_xor(csum, 32);                                       \
        l_i = l_i * al + csum;                                              \
        m_i = mn;                                                           \
    } while (0)

#define PS_WRITE(BUF)                                                       \
    do {                                                                    \
        const int n = w * 16 + col;                                         \
        _Pragma("unroll")                                                   \
        for (int mt = 0; mt < 4; ++mt) {                                    \
            const int p_log = 2 * mt + (q4 >> 1);                           \
            const int p_phys = p_log ^ (n & 7);                             \
            *(half4*)((char*)&Ps[BUF][n * 64] + p_phys * 16 + (q4 & 1) * 8) = pk[mt]; \
        }                                                                   \
        if (q4 == 0) alph_s[BUF][n] = al;                                   \
    } while (0)

#define RESCALE(BUF)                                                        \
    do {                                                                    \
        float a0 = alph_s[BUF][col32];                                      \
        float a1 = alph_s[BUF][32 + col32];                                 \
        if (!__all((a0 == 1.0f) && (a1 == 1.0f))) {                         \
            _Pragma("unroll")                                               \
            for (int ct = 0; ct < 2; ++ct)                                  \
                _Pragma("unroll")                                           \
                for (int r = 0; r < 16; ++r) {                              \
                    acc[ct][0][r] *= a0;                                    \
                    acc[ct][1][r] *= a1;                                    \
                }                                                           \
        }                                                                   \
    } while (0)

#define PV_STEP(BUF)                                                        \
    do {                                                                    \
        __builtin_amdgcn_s_setprio(1);                                      \
        _Pragma("unroll")                                                   \
        for (int ks = 0; ks < 4; ++ks) {                                    \
            const int p_log = 2 * ks + h;                                   \
            half8 bp0 = *(const half8*)((char*)&Ps[BUF][col32 * 64] + (p_log ^ (col32 & 7)) * 16); \
            half8 bp1 = *(const half8*)((char*)&Ps[BUF][(32 + col32) * 64] + (p_log ^ (col32 & 7)) * 16); \
            _Pragma("unroll")                                               \
            for (int ct = 0; ct < 2; ++ct) {                                \
                const int c = w * 64 + ct * 32 + col32;                     \
                half8 av = *(const half8*)((char*)&vs[c * 64] + ((p_log ^ (c & 7)) * 16)); \
                acc[ct][0] = __builtin_amdgcn_mfma_f32_32x32x16_f16(av, bp0, acc[ct][0], 0, 0, 0); \
                acc[ct][1] = __builtin_amdgcn_mfma_f32_32x32x16_f16(av, bp1, acc[ct][1], 0, 0, 0); \
            }                                                               \
        }                                                                   \
        __builtin_amdgcn_s_setprio(0);                                      \
    } while (0)

    // ---- prologue: tile 0 through softmax ----
    K_LOAD(kbase);          // 4 VMEM (oldest)
    V_DMA(kbase);           // 8 VMEM
    QK_STEP();              // auto-wait on ak leaves V0 in flight
    { const int m1 = (1 < iters) ? kbase + 64 : kbase; K_LOAD(m1); }
    SM_STEP();
    PS_WRITE(0);

    for (int it = 0; it < iters - 1; ++it) {
        const int cur = it & 1, nxt = cur ^ 1;
        asm volatile("s_waitcnt lgkmcnt(0)" ::: "memory");
        __builtin_amdgcn_s_barrier();           // Ps[cur]/alph[cur] visible
        QK_STEP();                              // consumes ak = K(it+1)
        { const int m2 = (it + 2 < iters) ? kbase + (it + 2) * 64
                                          : kbase + (iters - 1) * 64;
          K_LOAD(m2); }
        RESCALE(cur);
        asm volatile("s_waitcnt vmcnt(4)" ::: "memory");  // V(it) landed
        PV_STEP(cur);
        SM_STEP();                              // overlaps PV drain (VALU pipe)
        PS_WRITE(nxt);
        asm volatile("s_waitcnt lgkmcnt(0)" ::: "memory"); // my PV reads retired
        V_DMA(kbase + (it + 1) * 64);
    }

    // ---- final tile ----
    {
        const int cur = (iters - 1) & 1;
        asm volatile("s_waitcnt lgkmcnt(0)" ::: "memory");
        __builtin_amdgcn_s_barrier();
        RESCALE(cur);
        asm volatile("s_waitcnt vmcnt(0)" ::: "memory");  // age order inverted: full drain
        PV_STEP(cur);
    }

    // ---- epilogue: normalized O (f16) + z = m + log2(l) ----
    if (q4 == 0) {
        const int n = w * 16 + col;
        l_s[n] = l_i;
        Ml[(size_t)(kh * 8 + b) * BN + n0 + n] = m_i + LOG2F(l_i);
    }
    __syncthreads();
    const float li0 = 1.0f / l_s[col32];
    const float li1 = 1.0f / l_s[32 + col32];

    _Float16* Opp = Op + (size_t)(kh * 8 + b) * NCH * BN;
#pragma unroll
    for (int ct = 0; ct < 2; ++ct)
#pragma unroll
        for (int nt = 0; nt < 2; ++nt) {
            const float li = nt ? li1 : li0;
#pragma unroll
            for (int r = 0; r < 16; ++r) {
                int row = (r & 3) + 8 * (r >> 2) + 4 * h;
                int c = w * 64 + ct * 32 + row;
                Opp[(size_t)c * BN + n0 + nt * 32 + col32] = (_Float16)(acc[ct][nt][r] * li);
            }
        }
#undef K_LOAD
#undef V_DMA
#undef QK_STEP
#undef SM_STEP
#undef PS_WRITE
#undef RESCALE
#undef PV_STEP
}

// ---------------------------------------------------------------------------
// Combine: z-softmax merge of nsplit normalized partials + x residual.
// x8 along n; grid (2, 128, 8) = 2048 blocks, 2 channels/block.
// ---------------------------------------------------------------------------
__global__ __launch_bounds__(256) void combine_kernel(
    const _Float16* __restrict__ Op, const float* __restrict__ Ml,
    const float* __restrict__ x, float* __restrict__ out, int nsplit)
{
    const int n  = (blockIdx.x * 256 + threadIdx.x) * 8;
    const int c0 = blockIdx.y * 2;
    const int b  = blockIdx.z;

    float f[3][8];
    float Z[8];
#pragma unroll
    for (int j = 0; j < 8; ++j) Z[j] = -1e30f;
    for (int s = 0; s < nsplit; ++s) {
        const float* mlp = &Ml[(size_t)(s * 8 + b) * BN + n];
        floatx4 z0 = *(const floatx4*)mlp;
        floatx4 z1 = *(const floatx4*)(mlp + 4);
#pragma unroll
        for (int j = 0; j < 4; ++j) { f[s][j] = z0[j]; f[s][4 + j] = z1[j]; }
#pragma unroll
        for (int j = 0; j < 8; ++j) Z[j] = fmaxf(Z[j], f[s][j]);
    }
    float lsum[8];
#pragma unroll
    for (int j = 0; j < 8; ++j) lsum[j] = 0.0f;
    for (int s = 0; s < nsplit; ++s)
#pragma unroll
        for (int j = 0; j < 8; ++j) { f[s][j] = EXP2F(f[s][j] - Z[j]); lsum[j] += f[s][j]; }
#pragma unroll
    for (int j = 0; j < 8; ++j) lsum[j] = 1.0f / lsum[j];
    for (int s = 0; s < nsplit; ++s)
#pragma unroll
        for (int j = 0; j < 8; ++j) f[s][j] *= lsum[j];

#pragma unroll 2
    for (int ci = 0; ci < 2; ++ci) {
        const int c = c0 + ci;
        const size_t off = ((size_t)b * NCH + c) * BN + n;
        const size_t po = (size_t)c * BN + n;
        float ov[8];
#pragma unroll
        for (int j = 0; j < 8; ++j) ov[j] = 0.0f;
        for (int s = 0; s < nsplit; ++s) {
            half8 hv = *(const half8*)&Op[(size_t)(s * 8 + b) * NCH * BN + po];
#pragma unroll
            for (int j = 0; j < 8; ++j) ov[j] += (float)hv[j] * f[s][j];
        }
        floatx4 x0 = *(const floatx4*)&x[off];
        floatx4 x1 = *(const floatx4*)&x[off + 4];
        floatx4 o0, o1;
#pragma unroll
        for (int j = 0; j < 4; ++j) { o0[j] = ov[j] + x0[j]; o1[j] = ov[4 + j] + x1[j]; }
        *(floatx4*)&out[off] = o0;
        *(floatx4*)&out[off + 4] = o1;
    }
}

extern "C" void kernel_launch(void* const* d_in, const int* in_sizes, int n_in,
                              void* d_out, int out_size, void* d_ws, size_t ws_size,
                              hipStream_t stream)
{
    const float* x  = (const float*)d_in[0];
    const float* Wq = (const float*)d_in[1];
    const float* bq = (const float*)d_in[2];
    const float* Wk = (const float*)d_in[3];
    const float* bk = (const float*)d_in[4];
    const float* Wv = (const float*)d_in[5];
    const float* bv = (const float*)d_in[6];
    float* out = (float*)d_out;

    _Float16* ws = (_Float16*)d_ws;
    _Float16* W16 = ws;                               // 81920 f16
    _Float16* qT  = W16 + 81920;                      // 8*4096*32 f16 (2 MB)
    _Float16* kT  = qT + (size_t)8 * BN * DQ;         // 2 MB
    _Float16* vb  = kT + (size_t)8 * BN * DQ;         // 16 MB
    _Float16* Op  = vb + (size_t)8 * NCH * BN;        // nsplit*16 MB

    // choose split count by available workspace
    const size_t baseElems = 81920 + (size_t)2 * 8 * BN * DQ + (size_t)8 * NCH * BN;
    const size_t opElems3  = (size_t)3 * 8 * NCH * BN;
    const size_t mlBytes   = (size_t)24 * BN * sizeof(float);
    const size_t need3     = (baseElems + opElems3) * 2 + mlBytes + 256;
    const int nsplit = (ws_size >= need3) ? 3 : 2;
    const int KPS    = (nsplit == 3) ? 1408 : 2048;

    float* Ml = (float*)(Op + (size_t)nsplit * 8 * NCH * BN);

    convert_w<<<dim3(80), 256, 0, stream>>>(Wq, Wk, Wv, W16);
    proj_kernel<<<dim3(32, 8), 512, 0, stream>>>(x, W16, bq, bk, bv, qT, kT, vb);
    flash_kernel<<<dim3(64, nsplit, 8), 256, 0, stream>>>(qT, kT, vb, Op, Ml, KPS);
    combine_kernel<<<dim3(2, 128, 8), 256, 0, stream>>>(Op, Ml, x, out, nsplit);
}